// Round 1
// baseline (444.340 us; speedup 1.0000x reference)
//
#include <hip/hip_runtime.h>

// out[M,N] = x[M,K] @ W_eff[N,K]^T + bias[N],  W_eff = W + 2.0*(B@A)
// M=8192 (4*2048), N=4096, K=4096, R=16.
// Strategy: fold rank-16 LoRA into W (rank-16 update), cast x and W_eff to
// bf16 in workspace, run m97-structure bf16 MFMA GEMM with bias epilogue.

typedef __attribute__((ext_vector_type(4))) float f32x4;
typedef __attribute__((ext_vector_type(8))) short bf16x8;

// round-to-nearest-even f32 -> bf16 bits
__device__ __forceinline__ unsigned short f2bf(float f) {
    unsigned u = __builtin_bit_cast(unsigned, f);
    unsigned r = u + 0x7fffu + ((u >> 16) & 1u);
    return (unsigned short)(r >> 16);
}

__device__ __forceinline__ void gload_lds16(const void* g, void* l) {
    __builtin_amdgcn_global_load_lds(
        (const __attribute__((address_space(1))) void*)g,
        (__attribute__((address_space(3))) void*)l, 16, 0, 0);
}

// ---------------- cast x (f32 -> bf16), 8 elems/thread/iter ----------------
__global__ __launch_bounds__(256) void cast_x_kernel(
    const float* __restrict__ x, unsigned short* __restrict__ xb, int n8)
{
    int stride = gridDim.x * blockDim.x;
    for (int i = blockIdx.x * blockDim.x + threadIdx.x; i < n8; i += stride) {
        size_t base = (size_t)i * 8;
        float4 f0 = *(const float4*)&x[base];
        float4 f1 = *(const float4*)&x[base + 4];
        ushort4 o0, o1;
        o0.x = f2bf(f0.x); o0.y = f2bf(f0.y); o0.z = f2bf(f0.z); o0.w = f2bf(f0.w);
        o1.x = f2bf(f1.x); o1.y = f2bf(f1.y); o1.z = f2bf(f1.z); o1.w = f2bf(f1.w);
        *(ushort4*)&xb[base]     = o0;
        *(ushort4*)&xb[base + 4] = o1;
    }
}

// ------------- W_eff = W + scale * (B @ A), cast to bf16 -------------------
// grid: (K/256, N/16). block 256 = 4 waves; wave w handles 4 rows n, lane
// handles 4 consecutive k. B[16 rows][16 r] staged in LDS (broadcast reads).
__global__ __launch_bounds__(256) void prep_w_kernel(
    const float* __restrict__ W, const float* __restrict__ A,
    const float* __restrict__ Bl, unsigned short* __restrict__ wb,
    int K, float scale)
{
    __shared__ float Bs[16][16];
    const int t = threadIdx.x;
    const int n0 = blockIdx.y * 16;
    const int k0 = blockIdx.x * 256;
    {
        int nl = t >> 4, r = t & 15;
        Bs[nl][r] = Bl[(size_t)(n0 + nl) * 16 + r];
    }
    __syncthreads();

    const int lane = t & 63;
    const int wv = t >> 6;          // 0..3 -> rows n0+wv*4 .. +3
    const int k = k0 + lane * 4;

    float4 av[16];
#pragma unroll
    for (int r = 0; r < 16; ++r)
        av[r] = *(const float4*)&A[(size_t)r * K + k];

#pragma unroll
    for (int j = 0; j < 4; ++j) {
        const int nl = wv * 4 + j;
        const int n = n0 + nl;
        float4 w = *(const float4*)&W[(size_t)n * K + k];
        float d0 = 0.f, d1 = 0.f, d2 = 0.f, d3 = 0.f;
#pragma unroll
        for (int r = 0; r < 16; ++r) {
            float b = Bs[nl][r];
            d0 += b * av[r].x; d1 += b * av[r].y;
            d2 += b * av[r].z; d3 += b * av[r].w;
        }
        ushort4 o;
        o.x = f2bf(w.x + scale * d0);
        o.y = f2bf(w.y + scale * d1);
        o.z = f2bf(w.z + scale * d2);
        o.w = f2bf(w.w + scale * d3);
        *(ushort4*)&wb[(size_t)n * K + k] = o;
    }
}

// ---------------- bf16 GEMM (B^T layout) + bias, m97 structure -------------
// 128x128 tile, BK=32, 256 threads = 2x2 waves, each wave 64x64 out
// (4x4 fragments of 16x16x32 MFMA). global_load_lds width-16 staging.
__global__ __launch_bounds__(256) void gemm_bt_bias_kernel(
    const unsigned short* __restrict__ Xb, const unsigned short* __restrict__ Wb,
    const float* __restrict__ bias, float* __restrict__ out,
    int M, int N, int K)
{
    constexpr int BM = 128, BN = 128, BK = 32;
    __shared__ __align__(16) unsigned short As[BM * BK];
    __shared__ __align__(16) unsigned short Bs[BN * BK];

    const int ntn = N / BN;
    const int nwg = gridDim.x;
    int bid = blockIdx.x;
    if ((nwg & 7) == 0) {                 // XCD-aware swizzle (bijective here)
        int per = nwg >> 3;
        bid = (bid & 7) * per + (bid >> 3);
    }
    const int tm = bid / ntn, tn = bid % ntn;

    const int t = threadIdx.x;
    const int lane = t & 63, wave = t >> 6;
    const int wr = wave >> 1, wc = wave & 1;

    // staging: issue i in {0,1}: elem off = (i*256+t)*8 -> row=off/32 col=off%32
    const int soff = t * 8;
    const int srow = soff >> 5;           // 0..63
    const int scol = soff & 31;
    const size_t gA0 = (size_t)(tm * BM + srow) * K + scol;
    const size_t gB0 = (size_t)(tn * BN + srow) * K + scol;
    unsigned short* ldsA = &As[wave * 512];   // wave-uniform base, lane*16B auto
    unsigned short* ldsB = &Bs[wave * 512];

    f32x4 acc[4][4] = {};

    const int fr = lane & 15;             // frag row/col index
    const int fk = (lane >> 4) * 8;       // frag k offset

    for (int k0 = 0; k0 < K; k0 += BK) {
        __syncthreads();
        gload_lds16(Xb + gA0 + k0,                  ldsA);
        gload_lds16(Xb + gA0 + k0 + (size_t)64 * K, ldsA + 2048);
        gload_lds16(Wb + gB0 + k0,                  ldsB);
        gload_lds16(Wb + gB0 + k0 + (size_t)64 * K, ldsB + 2048);
        __syncthreads();

        bf16x8 a[4], b[4];
#pragma unroll
        for (int mi = 0; mi < 4; ++mi)
            a[mi] = *(const bf16x8*)&As[(wr * 64 + mi * 16 + fr) * BK + fk];
#pragma unroll
        for (int ni = 0; ni < 4; ++ni)
            b[ni] = *(const bf16x8*)&Bs[(wc * 64 + ni * 16 + fr) * BK + fk];

#pragma unroll
        for (int mi = 0; mi < 4; ++mi)
#pragma unroll
            for (int ni = 0; ni < 4; ++ni)
                acc[mi][ni] = __builtin_amdgcn_mfma_f32_16x16x32_bf16(
                    a[mi], b[ni], acc[mi][ni], 0, 0, 0);
    }

    // epilogue: C/D layout col = lane&15, row = (lane>>4)*4 + reg
    const int row0 = tm * BM + wr * 64;
    const int col0 = tn * BN + wc * 64;
    const int cr = (lane >> 4) * 4;
#pragma unroll
    for (int ni = 0; ni < 4; ++ni) {
        const int col = col0 + ni * 16 + fr;
        const float bv = bias[col];
#pragma unroll
        for (int mi = 0; mi < 4; ++mi) {
            const int row = row0 + mi * 16 + cr;
#pragma unroll
            for (int r = 0; r < 4; ++r)
                out[(size_t)(row + r) * N + col] = acc[mi][ni][r] + bv;
        }
    }
}

extern "C" void kernel_launch(void* const* d_in, const int* in_sizes, int n_in,
                              void* d_out, int out_size, void* d_ws, size_t ws_size,
                              hipStream_t stream)
{
    const float* x  = (const float*)d_in[0];   // [B,S,Din]
    const float* W  = (const float*)d_in[1];   // [Dout,Din]
    const float* b  = (const float*)d_in[2];   // [Dout]
    const float* A  = (const float*)d_in[3];   // [R,Din]
    const float* Bl = (const float*)d_in[4];   // [Dout,R]
    float* out = (float*)d_out;

    const int Dout = in_sizes[2];              // 4096
    const int Din  = in_sizes[1] / Dout;       // 4096
    const int M    = in_sizes[0] / Din;        // 8192

    unsigned short* xb = (unsigned short*)d_ws;           // M*Din bf16
    unsigned short* wb = xb + (size_t)M * Din;            // Dout*Din bf16

    cast_x_kernel<<<2048, 256, 0, stream>>>(x, xb, M * Din / 8);

    dim3 gw(Din / 256, Dout / 16);
    prep_w_kernel<<<gw, 256, 0, stream>>>(W, A, Bl, wb, Din, 2.0f);

    const int grid = (M / 128) * (Dout / 128); // 2048
    gemm_bt_bias_kernel<<<grid, 256, 0, stream>>>(xb, wb, b, out, M, Dout, Din);
}

// Round 2
// 323.096 us; speedup vs baseline: 1.3753x; 1.3753x over previous
//
#include <hip/hip_runtime.h>

// out[M,N] = x[M,K] @ W_eff[N,K]^T + bias[N],  W_eff = W + 2.0*(B@A)
// M=8192, N=4096, K=4096, R=16.
// Round 2: 256x256 8-phase GEMM (T2 swizzle + T3/T4 counted vmcnt + T5 setprio).

typedef __attribute__((ext_vector_type(4))) float f32x4;
typedef __attribute__((ext_vector_type(8))) short bf16x8;

__device__ __forceinline__ unsigned short f2bf(float f) {
    unsigned u = __builtin_bit_cast(unsigned, f);
    unsigned r = u + 0x7fffu + ((u >> 16) & 1u);
    return (unsigned short)(r >> 16);
}

__device__ __forceinline__ void gload_lds16(const void* g, void* l) {
    __builtin_amdgcn_global_load_lds(
        (const __attribute__((address_space(1))) void*)g,
        (__attribute__((address_space(3))) void*)l, 16, 0, 0);
}

// ---------------- cast x (f32 -> bf16) ----------------
__global__ __launch_bounds__(256) void cast_x_kernel(
    const float* __restrict__ x, unsigned short* __restrict__ xb, int n8)
{
    int stride = gridDim.x * blockDim.x;
    for (int i = blockIdx.x * blockDim.x + threadIdx.x; i < n8; i += stride) {
        size_t base = (size_t)i * 8;
        float4 f0 = *(const float4*)&x[base];
        float4 f1 = *(const float4*)&x[base + 4];
        ushort4 o0, o1;
        o0.x = f2bf(f0.x); o0.y = f2bf(f0.y); o0.z = f2bf(f0.z); o0.w = f2bf(f0.w);
        o1.x = f2bf(f1.x); o1.y = f2bf(f1.y); o1.z = f2bf(f1.z); o1.w = f2bf(f1.w);
        *(ushort4*)&xb[base]     = o0;
        *(ushort4*)&xb[base + 4] = o1;
    }
}

// ------------- W_eff = W + scale*(B@A), cast to bf16 -------------
__global__ __launch_bounds__(256) void prep_w_kernel(
    const float* __restrict__ W, const float* __restrict__ A,
    const float* __restrict__ Bl, unsigned short* __restrict__ wb,
    int K, float scale)
{
    __shared__ float Bs[16][16];
    const int t = threadIdx.x;
    const int n0 = blockIdx.y * 16;
    const int k0 = blockIdx.x * 256;
    {
        int nl = t >> 4, r = t & 15;
        Bs[nl][r] = Bl[(size_t)(n0 + nl) * 16 + r];
    }
    __syncthreads();

    const int lane = t & 63;
    const int wv = t >> 6;
    const int k = k0 + lane * 4;

    float4 av[16];
#pragma unroll
    for (int r = 0; r < 16; ++r)
        av[r] = *(const float4*)&A[(size_t)r * K + k];

#pragma unroll
    for (int j = 0; j < 4; ++j) {
        const int nl = wv * 4 + j;
        const int n = n0 + nl;
        float4 w = *(const float4*)&W[(size_t)n * K + k];
        float d0 = 0.f, d1 = 0.f, d2 = 0.f, d3 = 0.f;
#pragma unroll
        for (int r = 0; r < 16; ++r) {
            float b = Bs[nl][r];
            d0 += b * av[r].x; d1 += b * av[r].y;
            d2 += b * av[r].z; d3 += b * av[r].w;
        }
        ushort4 o;
        o.x = f2bf(w.x + scale * d0);
        o.y = f2bf(w.y + scale * d1);
        o.z = f2bf(w.z + scale * d2);
        o.w = f2bf(w.w + scale * d3);
        *(ushort4*)&wb[(size_t)n * K + k] = o;
    }
}

// ---------------- 256x256 8-phase bf16 GEMM + bias ----------------
// 512 threads = 8 waves (2 M x 4 N), each wave owns 128x64 output.
// LDS [dbuf][A/B][half][128*64 bf16] = 128 KiB. BK=64, 4 phases/K-tile.
// Swizzle: byte ^= (row&7)<<4, applied on global-source col AND ds_read addr
// (LDS dest stays linear for global_load_lds).

#define SETPRIO(p) __builtin_amdgcn_s_setprio(p)
#define BARRIER()  __builtin_amdgcn_s_barrier()

__global__ __launch_bounds__(512, 2) void gemm256_kernel(
    const unsigned short* __restrict__ Xb, const unsigned short* __restrict__ Wb,
    const float* __restrict__ bias, float* __restrict__ out,
    int M, int N, int K)
{
    __shared__ __align__(16) unsigned short lds[2][2][2][8192];

    const int NT = K / 64;
    const int ntn = N / 256;
    int bid = blockIdx.x;
    {   // XCD swizzle (grid 512, divisible by 8 -> simple form bijective)
        int per = gridDim.x >> 3;
        bid = (bid & 7) * per + (bid >> 3);
    }
    const int tm = bid / ntn, tn = bid % ntn;

    const int t = threadIdx.x;
    const int lane = t & 63, wave = t >> 6;
    const int wr = wave >> 2;          // 0..1 -> A half, rows wr*128
    const int wc = wave & 3;           // 0..3 -> cols wc*64

    // ---- staging addresses (pre-swizzled global source, linear LDS dest) ----
    const int srow = t >> 3;                                   // 0..63
    const int scol = ((t & 7) * 8) ^ (((t >> 3) & 7) << 3);    // elements
    unsigned gA[2][2], gB[2][2];
#pragma unroll
    for (int h = 0; h < 2; ++h)
#pragma unroll
        for (int i = 0; i < 2; ++i) {
            gA[h][i] = (unsigned)((tm * 256 + h * 128 + i * 64 + srow) * K + scol);
            gB[h][i] = (unsigned)((tn * 256 + h * 128 + i * 64 + srow) * K + scol);
        }

#define STAGE_A(buf, kt)                                                        \
    _Pragma("unroll") for (int h = 0; h < 2; ++h)                               \
    _Pragma("unroll") for (int i = 0; i < 2; ++i)                               \
        gload_lds16(Xb + gA[h][i] + (kt) * 64,                                  \
                    &lds[buf][0][h][i * 4096 + wave * 512]);
#define STAGE_B(buf, kt)                                                        \
    _Pragma("unroll") for (int h = 0; h < 2; ++h)                               \
    _Pragma("unroll") for (int i = 0; i < 2; ++i)                               \
        gload_lds16(Wb + gB[h][i] + (kt) * 64,                                  \
                    &lds[buf][1][h][i * 4096 + wave * 512]);

    // ---- fragment read offsets (swizzled) ----
    const int fr = lane & 15;
    const int hi16 = ((lane >> 4) & 3) * 16;       // k-offset bytes within row
    const int bsw = (fr & 7) << 4;
    const int lo0 = hi16 ^ bsw;                    // kk=0
    const int lo1 = (64 + hi16) ^ bsw;             // kk=1

    f32x4 acc[8][4] = {};
    bf16x8 a[8][2], b[4][2];

    // ---- prologue: stage tiles 0,1 ----
    STAGE_A(0, 0); STAGE_B(0, 0);
    STAGE_A(1, 1); STAGE_B(1, 1);
    asm volatile("s_waitcnt vmcnt(8)" ::: "memory");
    BARRIER();

    for (int kt = 0; kt < NT; ++kt) {
        const int cur = kt & 1;
        const char* pA = (const char*)&lds[cur][0][wr][0];
        const char* pB = (const char*)&lds[cur][1][wc >> 1][0];
        const int bro = (wc & 1) * 64;   // B row offset within half

        // ---- P1: read A-lo + B-lo, MFMA Q0 (mi0-3 x ni0-1) ----
#pragma unroll
        for (int mi = 0; mi < 4; ++mi) {
            a[mi][0] = *(const bf16x8*)(pA + (mi * 16 + fr) * 128 + lo0);
            a[mi][1] = *(const bf16x8*)(pA + (mi * 16 + fr) * 128 + lo1);
        }
#pragma unroll
        for (int ni = 0; ni < 2; ++ni) {
            b[ni][0] = *(const bf16x8*)(pB + (bro + ni * 16 + fr) * 128 + lo0);
            b[ni][1] = *(const bf16x8*)(pB + (bro + ni * 16 + fr) * 128 + lo1);
        }
        BARRIER();
        SETPRIO(1);
#pragma unroll
        for (int mi = 0; mi < 4; ++mi)
#pragma unroll
            for (int ni = 0; ni < 2; ++ni)
#pragma unroll
                for (int kk = 0; kk < 2; ++kk)
                    acc[mi][ni] = __builtin_amdgcn_mfma_f32_16x16x32_bf16(
                        a[mi][kk], b[ni][kk], acc[mi][ni], 0, 0, 0);
        SETPRIO(0);
        BARRIER();

        // ---- P2: read A-hi + B-hi, MFMA Q1 (mi0-3 x ni2-3) ----
#pragma unroll
        for (int mi = 4; mi < 8; ++mi) {
            a[mi][0] = *(const bf16x8*)(pA + (mi * 16 + fr) * 128 + lo0);
            a[mi][1] = *(const bf16x8*)(pA + (mi * 16 + fr) * 128 + lo1);
        }
#pragma unroll
        for (int ni = 2; ni < 4; ++ni) {
            b[ni][0] = *(const bf16x8*)(pB + (bro + ni * 16 + fr) * 128 + lo0);
            b[ni][1] = *(const bf16x8*)(pB + (bro + ni * 16 + fr) * 128 + lo1);
        }
        BARRIER();
        SETPRIO(1);
#pragma unroll
        for (int mi = 0; mi < 4; ++mi)
#pragma unroll
            for (int ni = 2; ni < 4; ++ni)
#pragma unroll
                for (int kk = 0; kk < 2; ++kk)
                    acc[mi][ni] = __builtin_amdgcn_mfma_f32_16x16x32_bf16(
                        a[mi][kk], b[ni][kk], acc[mi][ni], 0, 0, 0);
        SETPRIO(0);
        // all reads of buf[cur] complete before it gets re-staged in P3/P4
        asm volatile("s_waitcnt lgkmcnt(0)" ::: "memory");
        BARRIER();

        // ---- P3: stage A halves of tile kt+2 (same buffer), MFMA Q2 ----
        if (kt + 2 < NT) { STAGE_A(cur, kt + 2); }
        BARRIER();
        SETPRIO(1);
#pragma unroll
        for (int mi = 4; mi < 8; ++mi)
#pragma unroll
            for (int ni = 0; ni < 2; ++ni)
#pragma unroll
                for (int kk = 0; kk < 2; ++kk)
                    acc[mi][ni] = __builtin_amdgcn_mfma_f32_16x16x32_bf16(
                        a[mi][kk], b[ni][kk], acc[mi][ni], 0, 0, 0);
        SETPRIO(0);
        BARRIER();

        // ---- P4: stage B halves of kt+2, counted vmcnt, MFMA Q3 ----
        if (kt + 2 < NT) {
            STAGE_B(cur, kt + 2);
            asm volatile("s_waitcnt vmcnt(8)" ::: "memory");
        } else {
            asm volatile("s_waitcnt vmcnt(0)" ::: "memory");
        }
        BARRIER();
        SETPRIO(1);
#pragma unroll
        for (int mi = 4; mi < 8; ++mi)
#pragma unroll
            for (int ni = 2; ni < 4; ++ni)
#pragma unroll
                for (int kk = 0; kk < 2; ++kk)
                    acc[mi][ni] = __builtin_amdgcn_mfma_f32_16x16x32_bf16(
                        a[mi][kk], b[ni][kk], acc[mi][ni], 0, 0, 0);
        SETPRIO(0);
        BARRIER();
    }

    // ---- epilogue: C/D layout col=lane&15, row=(lane>>4)*4+reg ----
    const int row0 = tm * 256 + wr * 128 + (lane >> 4) * 4;
    const int col0 = tn * 256 + wc * 64;
#pragma unroll
    for (int ni = 0; ni < 4; ++ni) {
        const int col = col0 + ni * 16 + fr;
        const float bv = bias[col];
#pragma unroll
        for (int mi = 0; mi < 8; ++mi) {
            const int row = row0 + mi * 16;
#pragma unroll
            for (int r = 0; r < 4; ++r)
                out[(size_t)(row + r) * N + col] = acc[mi][ni][r] + bv;
        }
    }
}

extern "C" void kernel_launch(void* const* d_in, const int* in_sizes, int n_in,
                              void* d_out, int out_size, void* d_ws, size_t ws_size,
                              hipStream_t stream)
{
    const float* x  = (const float*)d_in[0];
    const float* W  = (const float*)d_in[1];
    const float* b  = (const float*)d_in[2];
    const float* A  = (const float*)d_in[3];
    const float* Bl = (const float*)d_in[4];
    float* out = (float*)d_out;

    const int Dout = in_sizes[2];
    const int Din  = in_sizes[1] / Dout;
    const int M    = in_sizes[0] / Din;

    unsigned short* xb = (unsigned short*)d_ws;
    unsigned short* wb = xb + (size_t)M * Din;

    cast_x_kernel<<<2048, 256, 0, stream>>>(x, xb, M * Din / 8);

    dim3 gw(Din / 256, Dout / 16);
    prep_w_kernel<<<gw, 256, 0, stream>>>(W, A, Bl, wb, Din, 2.0f);

    const int grid = (M / 256) * (Dout / 256); // 512
    gemm256_kernel<<<grid, 512, 0, stream>>>(xb, wb, b, out, M, Dout, Din);
}

// Round 3
// 322.270 us; speedup vs baseline: 1.3788x; 1.0026x over previous
//
#include <hip/hip_runtime.h>

// out[M,N] = x[M,K] @ W_eff[N,K]^T + bias[N],  W_eff = W + 2.0*(B@A)
// M=8192, N=4096, K=4096, R=16.
// Round 3: 256x256 dbuf GEMM, minimal barriers (2/K-tile), counted vmcnt(8),
// T2 LDS XOR-swizzle (0 conflicts), T1 XCD swizzle. Reads+MFMA in one
// barrier-free region -> cross-wave slip + compiler fine-lgkm interleave.

typedef __attribute__((ext_vector_type(4))) float f32x4;
typedef __attribute__((ext_vector_type(8))) short bf16x8;

__device__ __forceinline__ unsigned short f2bf(float f) {
    unsigned u = __builtin_bit_cast(unsigned, f);
    unsigned r = u + 0x7fffu + ((u >> 16) & 1u);
    return (unsigned short)(r >> 16);
}

__device__ __forceinline__ void gload_lds16(const void* g, void* l) {
    __builtin_amdgcn_global_load_lds(
        (const __attribute__((address_space(1))) void*)g,
        (__attribute__((address_space(3))) void*)l, 16, 0, 0);
}

// ---------------- cast x (f32 -> bf16) ----------------
__global__ __launch_bounds__(256) void cast_x_kernel(
    const float* __restrict__ x, unsigned short* __restrict__ xb, int n8)
{
    int stride = gridDim.x * blockDim.x;
    for (int i = blockIdx.x * blockDim.x + threadIdx.x; i < n8; i += stride) {
        size_t base = (size_t)i * 8;
        float4 f0 = *(const float4*)&x[base];
        float4 f1 = *(const float4*)&x[base + 4];
        ushort4 o0, o1;
        o0.x = f2bf(f0.x); o0.y = f2bf(f0.y); o0.z = f2bf(f0.z); o0.w = f2bf(f0.w);
        o1.x = f2bf(f1.x); o1.y = f2bf(f1.y); o1.z = f2bf(f1.z); o1.w = f2bf(f1.w);
        *(ushort4*)&xb[base]     = o0;
        *(ushort4*)&xb[base + 4] = o1;
    }
}

// ------------- W_eff = W + scale*(B@A), cast to bf16 -------------
__global__ __launch_bounds__(256) void prep_w_kernel(
    const float* __restrict__ W, const float* __restrict__ A,
    const float* __restrict__ Bl, unsigned short* __restrict__ wb,
    int K, float scale)
{
    __shared__ float Bs[16][16];
    const int t = threadIdx.x;
    const int n0 = blockIdx.y * 16;
    const int k0 = blockIdx.x * 256;
    {
        int nl = t >> 4, r = t & 15;
        Bs[nl][r] = Bl[(size_t)(n0 + nl) * 16 + r];
    }
    __syncthreads();

    const int lane = t & 63;
    const int wv = t >> 6;
    const int k = k0 + lane * 4;

    float4 av[16];
#pragma unroll
    for (int r = 0; r < 16; ++r)
        av[r] = *(const float4*)&A[(size_t)r * K + k];

#pragma unroll
    for (int j = 0; j < 4; ++j) {
        const int nl = wv * 4 + j;
        const int n = n0 + nl;
        float4 w = *(const float4*)&W[(size_t)n * K + k];
        float d0 = 0.f, d1 = 0.f, d2 = 0.f, d3 = 0.f;
#pragma unroll
        for (int r = 0; r < 16; ++r) {
            float b = Bs[nl][r];
            d0 += b * av[r].x; d1 += b * av[r].y;
            d2 += b * av[r].z; d3 += b * av[r].w;
        }
        ushort4 o;
        o.x = f2bf(w.x + scale * d0);
        o.y = f2bf(w.y + scale * d1);
        o.z = f2bf(w.z + scale * d2);
        o.w = f2bf(w.w + scale * d3);
        *(ushort4*)&wb[(size_t)n * K + k] = o;
    }
}

// ---------------- 256x256 bf16 GEMM + bias, 2-barrier/K-tile ----------------
// 512 threads = 8 waves (2 M x 4 N), each wave owns 128x64 output.
// LDS [dbuf][A/B][half][128*64 bf16] = 128 KiB. BK=64.
// Swizzle: byte ^= (row&7)<<4 via pre-swizzled global source + swizzled read.

#define BARRIER()  __builtin_amdgcn_s_barrier()

__global__ __launch_bounds__(512, 2) void gemm256_kernel(
    const unsigned short* __restrict__ Xb, const unsigned short* __restrict__ Wb,
    const float* __restrict__ bias, float* __restrict__ out,
    int M, int N, int K)
{
    __shared__ __align__(16) unsigned short lds[2][2][2][8192];

    const int NT = K / 64;
    const int ntn = N / 256;
    int bid = blockIdx.x;
    {   // XCD swizzle (grid 512, divisible by 8 -> simple form bijective)
        int per = gridDim.x >> 3;
        bid = (bid & 7) * per + (bid >> 3);
    }
    const int tm = bid / ntn, tn = bid % ntn;

    const int t = threadIdx.x;
    const int lane = t & 63, wave = t >> 6;
    const int wr = wave >> 2;          // 0..1 -> A half, rows wr*128
    const int wc = wave & 3;           // 0..3 -> cols wc*64

    // ---- staging addresses (pre-swizzled global source, linear LDS dest) ----
    const int srow = t >> 3;                                   // 0..63
    const int scol = ((t & 7) * 8) ^ (((t >> 3) & 7) << 3);    // elements
    unsigned gA[2][2], gB[2][2];
#pragma unroll
    for (int h = 0; h < 2; ++h)
#pragma unroll
        for (int i = 0; i < 2; ++i) {
            gA[h][i] = (unsigned)((tm * 256 + h * 128 + i * 64 + srow) * K + scol);
            gB[h][i] = (unsigned)((tn * 256 + h * 128 + i * 64 + srow) * K + scol);
        }

#define STAGE_A(buf, kt)                                                        \
    _Pragma("unroll") for (int h = 0; h < 2; ++h)                               \
    _Pragma("unroll") for (int i = 0; i < 2; ++i)                               \
        gload_lds16(Xb + gA[h][i] + (kt) * 64,                                  \
                    &lds[buf][0][h][i * 4096 + wave * 512]);
#define STAGE_B(buf, kt)                                                        \
    _Pragma("unroll") for (int h = 0; h < 2; ++h)                               \
    _Pragma("unroll") for (int i = 0; i < 2; ++i)                               \
        gload_lds16(Wb + gB[h][i] + (kt) * 64,                                  \
                    &lds[buf][1][h][i * 4096 + wave * 512]);

    // ---- fragment read offsets (swizzled) ----
    const int fr = lane & 15;
    const int hi16 = ((lane >> 4) & 3) * 16;       // k-offset bytes within row
    const int bsw = (fr & 7) << 4;
    const int lo0 = hi16 ^ bsw;                    // kk=0
    const int lo1 = (64 + hi16) ^ bsw;             // kk=1

    f32x4 acc[8][4] = {};

    // ---- prologue: stage tiles 0,1 ----
    STAGE_A(0, 0); STAGE_B(0, 0);
    STAGE_A(1, 1); STAGE_B(1, 1);
    asm volatile("s_waitcnt vmcnt(8)" ::: "memory");
    BARRIER();

    for (int kt = 0; kt < NT; ++kt) {
        const int cur = kt & 1;
        const char* pA = (const char*)&lds[cur][0][wr][0];
        const char* pB = (const char*)&lds[cur][1][wc >> 1][0];
        const int bro = (wc & 1) * 64;   // B row offset within half

        // ---- all fragment reads for this K-tile (compiler fine-lgkm) ----
        bf16x8 a[8][2], b[4][2];
#pragma unroll
        for (int mi = 0; mi < 8; ++mi) {
            a[mi][0] = *(const bf16x8*)(pA + (mi * 16 + fr) * 128 + lo0);
            a[mi][1] = *(const bf16x8*)(pA + (mi * 16 + fr) * 128 + lo1);
        }
#pragma unroll
        for (int ni = 0; ni < 4; ++ni) {
            b[ni][0] = *(const bf16x8*)(pB + (bro + ni * 16 + fr) * 128 + lo0);
            b[ni][1] = *(const bf16x8*)(pB + (bro + ni * 16 + fr) * 128 + lo1);
        }

        // ---- 64 MFMAs, kk0 first (dep only on first 12 reads) ----
#pragma unroll
        for (int kk = 0; kk < 2; ++kk)
#pragma unroll
            for (int mi = 0; mi < 8; ++mi)
#pragma unroll
                for (int ni = 0; ni < 4; ++ni)
                    acc[mi][ni] = __builtin_amdgcn_mfma_f32_16x16x32_bf16(
                        a[mi][kk], b[ni][kk], acc[mi][ni], 0, 0, 0);

        // ---- sync tail: drain reads of buf[cur], re-stage it with kt+2 ----
        asm volatile("s_waitcnt lgkmcnt(0)" ::: "memory");
        BARRIER();
        if (kt + 2 < NT) {
            STAGE_A(cur, kt + 2); STAGE_B(cur, kt + 2);
            asm volatile("s_waitcnt vmcnt(8)" ::: "memory");  // kt+1 landed
        } else {
            asm volatile("s_waitcnt vmcnt(0)" ::: "memory");
        }
        BARRIER();
    }

    // ---- epilogue: C/D layout col=lane&15, row=(lane>>4)*4+reg ----
    const int row0 = tm * 256 + wr * 128 + (lane >> 4) * 4;
    const int col0 = tn * 256 + wc * 64;
#pragma unroll
    for (int ni = 0; ni < 4; ++ni) {
        const int col = col0 + ni * 16 + fr;
        const float bv = bias[col];
#pragma unroll
        for (int mi = 0; mi < 8; ++mi) {
            const int row = row0 + mi * 16;
#pragma unroll
            for (int r = 0; r < 4; ++r)
                out[(size_t)(row + r) * N + col] = acc[mi][ni][r] + bv;
        }
    }
}

extern "C" void kernel_launch(void* const* d_in, const int* in_sizes, int n_in,
                              void* d_out, int out_size, void* d_ws, size_t ws_size,
                              hipStream_t stream)
{
    const float* x  = (const float*)d_in[0];
    const float* W  = (const float*)d_in[1];
    const float* b  = (const float*)d_in[2];
    const float* A  = (const float*)d_in[3];
    const float* Bl = (const float*)d_in[4];
    float* out = (float*)d_out;

    const int Dout = in_sizes[2];
    const int Din  = in_sizes[1] / Dout;
    const int M    = in_sizes[0] / Din;

    unsigned short* xb = (unsigned short*)d_ws;
    unsigned short* wb = xb + (size_t)M * Din;

    cast_x_kernel<<<2048, 256, 0, stream>>>(x, xb, M * Din / 8);

    dim3 gw(Din / 256, Dout / 16);
    prep_w_kernel<<<gw, 256, 0, stream>>>(W, A, Bl, wb, Din, 2.0f);

    const int grid = (M / 256) * (Dout / 256); // 512
    gemm256_kernel<<<grid, 512, 0, stream>>>(xb, wb, b, out, M, Dout, Din);
}

// Round 4
// 306.472 us; speedup vs baseline: 1.4499x; 1.0515x over previous
//
#include <hip/hip_runtime.h>

// out[M,N] = x[M,K] @ W_eff[N,K]^T + bias[N],  W_eff = W + 2.0*(B@A)
// M=8192, N=4096, K=4096, R=16.
// Round 4: faithful m201-style 8-phase schedule: per-phase fine interleave
// {ds_read quadrant subtile | stage 2 gload_lds | barrier | lgkm0 | 16 MFMA},
// staging spread 2 loads/phase (B->kt+1 at P1/P2, A->kt+2 at P3/P4),
// single counted vmcnt(4)/K-tile after P4 MFMA. T1 XCD swizzle, T2 XOR
// swizzle (0 conflicts), T5 setprio.

typedef __attribute__((ext_vector_type(4))) float f32x4;
typedef __attribute__((ext_vector_type(8))) short bf16x8;

__device__ __forceinline__ unsigned short f2bf(float f) {
    unsigned u = __builtin_bit_cast(unsigned, f);
    unsigned r = u + 0x7fffu + ((u >> 16) & 1u);
    return (unsigned short)(r >> 16);
}

__device__ __forceinline__ void gload_lds16(const void* g, void* l) {
    __builtin_amdgcn_global_load_lds(
        (const __attribute__((address_space(1))) void*)g,
        (__attribute__((address_space(3))) void*)l, 16, 0, 0);
}

// ---------------- cast x (f32 -> bf16) ----------------
__global__ __launch_bounds__(256) void cast_x_kernel(
    const float* __restrict__ x, unsigned short* __restrict__ xb, int n8)
{
    int stride = gridDim.x * blockDim.x;
    for (int i = blockIdx.x * blockDim.x + threadIdx.x; i < n8; i += stride) {
        size_t base = (size_t)i * 8;
        float4 f0 = *(const float4*)&x[base];
        float4 f1 = *(const float4*)&x[base + 4];
        ushort4 o0, o1;
        o0.x = f2bf(f0.x); o0.y = f2bf(f0.y); o0.z = f2bf(f0.z); o0.w = f2bf(f0.w);
        o1.x = f2bf(f1.x); o1.y = f2bf(f1.y); o1.z = f2bf(f1.z); o1.w = f2bf(f1.w);
        *(ushort4*)&xb[base]     = o0;
        *(ushort4*)&xb[base + 4] = o1;
    }
}

// ------------- W_eff = W + scale*(B@A), cast to bf16 -------------
__global__ __launch_bounds__(256) void prep_w_kernel(
    const float* __restrict__ W, const float* __restrict__ A,
    const float* __restrict__ Bl, unsigned short* __restrict__ wb,
    int K, float scale)
{
    __shared__ float Bs[16][16];
    const int t = threadIdx.x;
    const int n0 = blockIdx.y * 16;
    const int k0 = blockIdx.x * 256;
    {
        int nl = t >> 4, r = t & 15;
        Bs[nl][r] = Bl[(size_t)(n0 + nl) * 16 + r];
    }
    __syncthreads();

    const int lane = t & 63;
    const int wv = t >> 6;
    const int k = k0 + lane * 4;

    float4 av[16];
#pragma unroll
    for (int r = 0; r < 16; ++r)
        av[r] = *(const float4*)&A[(size_t)r * K + k];

#pragma unroll
    for (int j = 0; j < 4; ++j) {
        const int nl = wv * 4 + j;
        const int n = n0 + nl;
        float4 w = *(const float4*)&W[(size_t)n * K + k];
        float d0 = 0.f, d1 = 0.f, d2 = 0.f, d3 = 0.f;
#pragma unroll
        for (int r = 0; r < 16; ++r) {
            float b = Bs[nl][r];
            d0 += b * av[r].x; d1 += b * av[r].y;
            d2 += b * av[r].z; d3 += b * av[r].w;
        }
        ushort4 o;
        o.x = f2bf(w.x + scale * d0);
        o.y = f2bf(w.y + scale * d1);
        o.z = f2bf(w.z + scale * d2);
        o.w = f2bf(w.w + scale * d3);
        *(ushort4*)&wb[(size_t)n * K + k] = o;
    }
}

// ---------------- 256x256 8-phase bf16 GEMM + bias ----------------
// 512 threads = 8 waves (2 M x 4 N), each wave owns 128x64 output.
// LDS [dbuf][A/B][half][128*64 bf16] = 128 KiB. BK=64.
// Swizzle: byte ^= (row&7)<<4 via pre-swizzled global source + swizzled read.

#define SETPRIO(p) __builtin_amdgcn_s_setprio(p)
#define BARRIER()  __builtin_amdgcn_s_barrier()
#define LGKM0()    do { asm volatile("s_waitcnt lgkmcnt(0)" ::: "memory"); \
                        __builtin_amdgcn_sched_barrier(0); } while (0)

__global__ __launch_bounds__(512, 2) void gemm256_kernel(
    const unsigned short* __restrict__ Xb, const unsigned short* __restrict__ Wb,
    const float* __restrict__ bias, float* __restrict__ out,
    int M, int N, int K)
{
    __shared__ __align__(16) unsigned short lds[2][2][2][8192];

    const int NT = K / 64;
    const int ntn = N / 256;
    int bid = blockIdx.x;
    {   // XCD swizzle (grid 512, divisible by 8 -> simple form bijective)
        int per = gridDim.x >> 3;
        bid = (bid & 7) * per + (bid >> 3);
    }
    const int tm = bid / ntn, tn = bid % ntn;

    const int t = threadIdx.x;
    const int lane = t & 63, wave = t >> 6;
    const int wr = wave >> 2;          // 0..1 -> A half, rows wr*128
    const int wc = wave & 3;           // 0..3 -> cols wc*64

    // ---- staging addresses (pre-swizzled global source, linear LDS dest) ----
    const int srow = t >> 3;                                   // 0..63
    const int scol = ((t & 7) * 8) ^ (((t >> 3) & 7) << 3);    // elements
    unsigned gA[2][2], gB[2][2];
#pragma unroll
    for (int h = 0; h < 2; ++h)
#pragma unroll
        for (int i = 0; i < 2; ++i) {
            gA[h][i] = (unsigned)((tm * 256 + h * 128 + i * 64 + srow) * K + scol);
            gB[h][i] = (unsigned)((tn * 256 + h * 128 + i * 64 + srow) * K + scol);
        }

    // one chunk = 64 rows x 64 cols = 1 gload_lds per thread
#define ST_A(buf, h, i, kt)                                                     \
    gload_lds16(Xb + gA[h][i] + (kt) * 64,                                      \
                &lds[buf][0][h][(i) * 4096 + wave * 512]);
#define ST_B(buf, h, i, kt)                                                     \
    gload_lds16(Wb + gB[h][i] + (kt) * 64,                                      \
                &lds[buf][1][h][(i) * 4096 + wave * 512]);

    // ---- fragment read offsets (swizzled) ----
    const int fr = lane & 15;
    const int hi16 = ((lane >> 4) & 3) * 16;       // k-offset bytes within row
    const int bsw = (fr & 7) << 4;
    const int lo0 = hi16 ^ bsw;                    // kk=0
    const int lo1 = (64 + hi16) ^ bsw;             // kk=1

    f32x4 acc[8][4] = {};

    // ---- prologue: A0,B0 -> buf0; A1 -> buf1 (12 loads) ----
#pragma unroll
    for (int h = 0; h < 2; ++h)
#pragma unroll
        for (int i = 0; i < 2; ++i) { ST_A(0, h, i, 0) ST_B(0, h, i, 0) }
#pragma unroll
    for (int h = 0; h < 2; ++h)
#pragma unroll
        for (int i = 0; i < 2; ++i) { ST_A(1, h, i, 1) }
    asm volatile("s_waitcnt vmcnt(4)" ::: "memory");   // A0,B0 landed; A1 in flight
    BARRIER();

#define MFMA_Q(m0, n0)                                                          \
    _Pragma("unroll") for (int mi = m0; mi < m0 + 4; ++mi)                      \
    _Pragma("unroll") for (int ni = n0; ni < n0 + 2; ++ni)                      \
    _Pragma("unroll") for (int kk = 0; kk < 2; ++kk)                            \
        acc[mi][ni] = __builtin_amdgcn_mfma_f32_16x16x32_bf16(                  \
            a[mi][kk], b[ni][kk], acc[mi][ni], 0, 0, 0);

    for (int kt = 0; kt < NT; ++kt) {
        const int cur = kt & 1;
        const char* pA = (const char*)&lds[cur][0][wr][0];
        const char* pB = (const char*)&lds[cur][1][wc >> 1][0];
        const int bro = (wc & 1) * 64;   // B row offset within half
        const bool stB = (kt + 1 < NT);  // B of kt+1 -> buf[cur^1]
        const bool stA = (kt + 2 < NT);  // A of kt+2 -> buf[cur]

        bf16x8 a[8][2], b[4][2];

        // ---- P1: read a0-3,b0-1 (12); stage B-h0 of kt+1; MFMA Q(0,0) ----
#pragma unroll
        for (int mi = 0; mi < 4; ++mi) {
            a[mi][0] = *(const bf16x8*)(pA + (mi * 16 + fr) * 128 + lo0);
            a[mi][1] = *(const bf16x8*)(pA + (mi * 16 + fr) * 128 + lo1);
        }
#pragma unroll
        for (int ni = 0; ni < 2; ++ni) {
            b[ni][0] = *(const bf16x8*)(pB + (bro + ni * 16 + fr) * 128 + lo0);
            b[ni][1] = *(const bf16x8*)(pB + (bro + ni * 16 + fr) * 128 + lo1);
        }
        if (stB) { ST_B(cur ^ 1, 0, 0, kt + 1) ST_B(cur ^ 1, 0, 1, kt + 1) }
        BARRIER();
        LGKM0();
        SETPRIO(1);
        MFMA_Q(0, 0)
        SETPRIO(0);
        BARRIER();

        // ---- P2: read a4-7 (8); stage B-h1 of kt+1; MFMA Q(4,0) ----
#pragma unroll
        for (int mi = 4; mi < 8; ++mi) {
            a[mi][0] = *(const bf16x8*)(pA + (mi * 16 + fr) * 128 + lo0);
            a[mi][1] = *(const bf16x8*)(pA + (mi * 16 + fr) * 128 + lo1);
        }
        if (stB) { ST_B(cur ^ 1, 1, 0, kt + 1) ST_B(cur ^ 1, 1, 1, kt + 1) }
        BARRIER();
        LGKM0();
        SETPRIO(1);
        MFMA_Q(4, 0)
        SETPRIO(0);
        BARRIER();

        // ---- P3: read b2-3 (4); stage A-h0 of kt+2; MFMA Q(0,2) ----
#pragma unroll
        for (int ni = 2; ni < 4; ++ni) {
            b[ni][0] = *(const bf16x8*)(pB + (bro + ni * 16 + fr) * 128 + lo0);
            b[ni][1] = *(const bf16x8*)(pB + (bro + ni * 16 + fr) * 128 + lo1);
        }
        if (stA) { ST_A(cur, 0, 0, kt + 2) ST_A(cur, 0, 1, kt + 2) }
        BARRIER();
        LGKM0();
        SETPRIO(1);
        MFMA_Q(0, 2)
        SETPRIO(0);
        BARRIER();

        // ---- P4: stage A-h1 of kt+2; MFMA Q(4,2); counted vmcnt ----
        if (stA) { ST_A(cur, 1, 0, kt + 2) ST_A(cur, 1, 1, kt + 2) }
        BARRIER();
        SETPRIO(1);
        MFMA_Q(4, 2)
        SETPRIO(0);
        if (stA) {   // leave only A-of-kt+2's 4 loads in flight
            asm volatile("s_waitcnt vmcnt(4)" ::: "memory");
        } else {
            asm volatile("s_waitcnt vmcnt(0)" ::: "memory");
        }
        BARRIER();
    }

    // ---- epilogue: C/D layout col=lane&15, row=(lane>>4)*4+reg ----
    const int row0 = tm * 256 + wr * 128 + (lane >> 4) * 4;
    const int col0 = tn * 256 + wc * 64;
#pragma unroll
    for (int ni = 0; ni < 4; ++ni) {
        const int col = col0 + ni * 16 + fr;
        const float bv = bias[col];
#pragma unroll
        for (int mi = 0; mi < 8; ++mi) {
            const int row = row0 + mi * 16;
#pragma unroll
            for (int r = 0; r < 4; ++r)
                out[(size_t)(row + r) * N + col] = acc[mi][ni][r] + bv;
        }
    }
}

extern "C" void kernel_launch(void* const* d_in, const int* in_sizes, int n_in,
                              void* d_out, int out_size, void* d_ws, size_t ws_size,
                              hipStream_t stream)
{
    const float* x  = (const float*)d_in[0];
    const float* W  = (const float*)d_in[1];
    const float* b  = (const float*)d_in[2];
    const float* A  = (const float*)d_in[3];
    const float* Bl = (const float*)d_in[4];
    float* out = (float*)d_out;

    const int Dout = in_sizes[2];
    const int Din  = in_sizes[1] / Dout;
    const int M    = in_sizes[0] / Din;

    unsigned short* xb = (unsigned short*)d_ws;
    unsigned short* wb = xb + (size_t)M * Din;

    cast_x_kernel<<<2048, 256, 0, stream>>>(x, xb, M * Din / 8);

    dim3 gw(Din / 256, Dout / 16);
    prep_w_kernel<<<gw, 256, 0, stream>>>(W, A, Bl, wb, Din, 2.0f);

    const int grid = (M / 256) * (Dout / 256); // 512
    gemm256_kernel<<<grid, 512, 0, stream>>>(xb, wb, b, out, M, Dout, Din);
}